// Round 22
// baseline (299.945 us; speedup 1.0000x reference)
//
#include <hip/hip_runtime.h>

#define N_NODES 100000
#define IN_CH   256
#define HID_D   64
#define NCLS    6
#define NE      1600000
#define WB      48          // padded bucket width (Poisson(16) max deg ~42; ovf guard)
#define OVF_CAP 4096
#define NPART   8           // = #XCDs
#define PSZ     (N_NODES / NPART)   // 12500
#define GEMMB   1563                   // ceil(N/64)

typedef unsigned short u16;
typedef unsigned int   u32;
typedef __attribute__((ext_vector_type(8))) short bf16x8;
typedef __attribute__((ext_vector_type(4))) float f32x4;
typedef __attribute__((ext_vector_type(2))) int   i32x2;

// ws layout (bytes)
#define OFF_CNT   0u                    // 100000*4 = 400000
#define OFF_OVFC  400000u               // 4
#define OFF_OVF   400128u               // 4096*2*4 -> 432896
#define OFF_COL   433152u               // 100000*48*4 -> 19,633,152
#define OFF_WT    19633152u             // 25600 u16 -> 19,684,352
#define OFF_G     19684480u             // 12,800,000 (bf16) -> 32,484,480
#define OFF_H     32484480u             // 12,800,000 (bf16) -> 45,284,480
// fragment-table element offsets (u16 units)
#define WT_W1 0
#define WT_W2 16384
#define WT_WP 20480
#define WT_WC 24576
#define WT_TOT 25600
#define Z_OFF 600000u                   // d_out f32: logits [0,600000), z rest

__device__ __forceinline__ u16 f2bf(float f) {
    u32 u = __float_as_uint(f);
    return (u16)((u + 0x7fffu + ((u >> 16) & 1u)) >> 16);   // RNE
}
__device__ __forceinline__ float bf2f(u16 h) {
    return __uint_as_float(((u32)h) << 16);
}

// ---- weights -> fragment tables; also zeroes cnt+ovfc (drops the memset) ----
__global__ __launch_bounds__(256) void k_wprep(const float* __restrict__ W1,
                                               const float* __restrict__ W2,
                                               const float* __restrict__ Wp,
                                               const float* __restrict__ Wc,
                                               u16* __restrict__ wt,
                                               int* __restrict__ cntz) {
    int m = blockIdx.x * 256 + threadIdx.x;       // grid exact: 100 blocks
    for (int i = m; i <= N_NODES; i += 25600) cntz[i] = 0;   // cnt + ovfc
    if (m >= WT_TOT) return;
    float v;
    if (m >= WT_WC) {                             // Wc: [2][64][8], c = l&15
        int i = m - WT_WC;
        int j = i & 7, l = (i >> 3) & 63, kk = i >> 9;
        int k = kk * 32 + (l >> 4) * 8 + j;
        int c = l & 15;
        v = (c < NCLS) ? Wc[k * NCLS + c] : 0.f;
    } else {                                      // W1/W2/Wp: [KK][4][64][8]
        const float* src; int i;
        if      (m < WT_W2) { src = W1; i = m - WT_W1; }
        else if (m < WT_WP) { src = W2; i = m - WT_W2; }
        else                { src = Wp; i = m - WT_WP; }
        int j = i & 7, l = (i >> 3) & 63, t = (i >> 9) & 3, kk = i >> 11;
        int k = kk * 32 + (l >> 4) * 8 + j;
        int c = t * 16 + (l & 15);
        v = src[k * 64 + c];
    }
    wt[m] = f2bf(v);
}

// ---- XCD-partitioned bucket fill (R12/R17 body) with ONE experiment:
// col written via atomicExch instead of plain store. Theory: plain global
// stores don't write-allocate in L2 on gfx950 (explains the persistent
// 64-96MB WRITE_SIZE for a 6.4MB payload across R8-R21, even when the
// per-XCD col slice fits L2). Atomics operate AT the L2 -> partially-filled
// lines stay resident and merge. Oracle: WRITE_SIZE <= 25MB.
__global__ __launch_bounds__(256) void k_fill(const int* __restrict__ ei,
                                              int* __restrict__ cnt,
                                              int* __restrict__ col,
                                              int* __restrict__ ovfc,
                                              int* __restrict__ ovf) {
    const int part = blockIdx.x & (NPART - 1);
    const int lo = part * PSZ;
    const int hi = lo + PSZ;
    const int e0 = (blockIdx.x >> 3) * 512 + threadIdx.x * 2;   // grid: (NE/512)*8
    i32x2 s2 = __builtin_nontemporal_load((const i32x2*)(ei + e0));
    i32x2 d2 = __builtin_nontemporal_load((const i32x2*)(ei + NE + e0));
#pragma unroll
    for (int j = 0; j < 2; ++j) {
        int s = s2[j];
        int d = d2[j];
        if (d < lo || d >= hi) continue;
        if ((u32)s >= (u32)N_NODES) continue;
        int p = atomicAdd(&cnt[d], 1);
        if (p < WB) {
            atomicExch(&col[(size_t)d * WB + p], s);   // store-at-L2 experiment
        } else {
            int k = atomicAdd(ovfc, 1);
            if (k < OVF_CAP) { ovf[2 * k] = s; ovf[2 * k + 1] = d; }
        }
    }
}

// ---- G = A @ W (bf16 out, UNSCALED; dinv applied in k_agg) ----
template <int KDIM, bool ABF16>
__global__ __launch_bounds__(256) void k_gemm(const void* __restrict__ A,
                                              const u16* __restrict__ wt,
                                              u16* __restrict__ G) {
    constexpr int KK = KDIM / 32;
    __shared__ __align__(16) u16 sB[KK * 2048];

    for (int idx = threadIdx.x * 8; idx < KK * 2048; idx += 2048)
        *(bf16x8*)&sB[idx] = *(const bf16x8*)&wt[idx];   // linear coalesced
    __syncthreads();

    const int lane = threadIdx.x & 63;
    const int wv   = threadIdx.x >> 6;
    const int row0 = blockIdx.x * 64 + wv * 16;
    const int g4   = lane >> 4;
    const int r16  = lane & 15;

    int arow = row0 + r16;
    int arow_c = arow < N_NODES ? arow : 0;

    f32x4 acc[4] = {{0,0,0,0},{0,0,0,0},{0,0,0,0},{0,0,0,0}};

#pragma unroll
    for (int kk = 0; kk < KK; ++kk) {
        bf16x8 a;
        if (ABF16) {
            a = *(const bf16x8*)((const u16*)A + (size_t)arow_c * KDIM + kk * 32 + g4 * 8);
        } else {
            const float* ap = (const float*)A + (size_t)arow_c * KDIM + kk * 32 + g4 * 8;
            float4 f0 = *(const float4*)ap;
            float4 f1 = *(const float4*)(ap + 4);
            a[0] = (short)f2bf(f0.x); a[1] = (short)f2bf(f0.y);
            a[2] = (short)f2bf(f0.z); a[3] = (short)f2bf(f0.w);
            a[4] = (short)f2bf(f1.x); a[5] = (short)f2bf(f1.y);
            a[6] = (short)f2bf(f1.z); a[7] = (short)f2bf(f1.w);
        }
#pragma unroll
        for (int t = 0; t < 4; ++t) {
            bf16x8 b = *(const bf16x8*)&sB[((kk * 4 + t) * 64 + lane) * 8];
            acc[t] = __builtin_amdgcn_mfma_f32_16x16x32_bf16(a, b, acc[t], 0, 0, 0);
        }
    }

#pragma unroll
    for (int r = 0; r < 4; ++r) {
        int row = row0 + g4 * 4 + r;
        if (row < N_NODES)
#pragma unroll
            for (int t = 0; t < 4; ++t)
                G[(size_t)row * 64 + t * 16 + r16] = f2bf(acc[t][r]);
    }
}

// ---- Hout = relu(dinv_i*(sum_e dinv_s*g_s + dinv_i*g_i) + b)  (G unscaled) ----
__global__ __launch_bounds__(256) void k_agg(const u16* __restrict__ G,
                                             const int* __restrict__ col,
                                             const int* __restrict__ cnt,
                                             const int* __restrict__ ovfc,
                                             const int* __restrict__ ovf,
                                             const float* __restrict__ bias,
                                             u16* __restrict__ Hout) {
    int node = blockIdx.x * 4 + (threadIdx.x >> 6);   // grid exact: N/4
    int lane = threadIdx.x & 63;

    int deg = cnt[node];
    int m = min(deg, WB);
    float dinv_i = rsqrtf((float)(deg + 1));

    int mycol = (lane < m) ? col[(size_t)node * WB + lane] : 0;  // guard poison
    float mydinv = rsqrtf((float)(cnt[mycol] + 1));

    float acc = dinv_i * bf2f(G[(size_t)node * 64 + lane]);      // self term

    int e = 0;
    for (; e + 4 <= m; e += 4) {
        int c0 = __shfl(mycol, e + 0), c1 = __shfl(mycol, e + 1);
        int c2 = __shfl(mycol, e + 2), c3 = __shfl(mycol, e + 3);
        float w0 = __shfl(mydinv, e + 0), w1 = __shfl(mydinv, e + 1);
        float w2 = __shfl(mydinv, e + 2), w3 = __shfl(mydinv, e + 3);
        acc += w0 * bf2f(G[(size_t)c0 * 64 + lane]);
        acc += w1 * bf2f(G[(size_t)c1 * 64 + lane]);
        acc += w2 * bf2f(G[(size_t)c2 * 64 + lane]);
        acc += w3 * bf2f(G[(size_t)c3 * 64 + lane]);
    }
    for (; e < m; ++e) {
        int c = __shfl(mycol, e);
        float w = __shfl(mydinv, e);
        acc += w * bf2f(G[(size_t)c * 64 + lane]);
    }

    int no = *ovfc;
    if (no > 0) {                        // ~never taken (deg > 48)
        no = min(no, OVF_CAP);
        for (int j = 0; j < no; ++j)
            if (ovf[2 * j + 1] == node) {
                int s = ovf[2 * j];
                acc += rsqrtf((float)(cnt[s] + 1)) * bf2f(G[(size_t)s * 64 + lane]);
            }
    }

    float v = fmaxf(dinv_i * acc + bias[lane], 0.f);
    Hout[(size_t)node * 64 + lane] = f2bf(v);
}

// ---- z = relu(H@Wp+bp) -> out f32 [Z_OFF..]; logits = z@Wc+bc -> out f32 ----
__global__ __launch_bounds__(256) void k_mlp(const u16* __restrict__ H,
                                             const u16* __restrict__ wt,
                                             const float* __restrict__ bp,
                                             const float* __restrict__ bc,
                                             float* __restrict__ out) {
    __shared__ __align__(16) u16 sP[2 * 2048];
    __shared__ __align__(16) u16 sC[1024];
    __shared__ __align__(16) u16 zt[4][16][72];

    for (int idx = threadIdx.x * 8; idx < 4096; idx += 2048)
        *(bf16x8*)&sP[idx] = *(const bf16x8*)&wt[WT_WP + idx];
    {
        int idx = threadIdx.x * 8;
        if (idx < 1024)
            *(bf16x8*)&sC[idx] = *(const bf16x8*)&wt[WT_WC + idx];
    }
    __syncthreads();

    const int lane = threadIdx.x & 63;
    const int wv   = threadIdx.x >> 6;
    const int row0 = blockIdx.x * 64 + wv * 16;
    const int g4   = lane >> 4;
    const int r16  = lane & 15;

    int arow = row0 + r16;
    int arow_c = arow < N_NODES ? arow : (N_NODES - 1);

    f32x4 zac[4] = {{0,0,0,0},{0,0,0,0},{0,0,0,0},{0,0,0,0}};
#pragma unroll
    for (int kk = 0; kk < 2; ++kk) {
        bf16x8 a = *(const bf16x8*)((const u16*)H + (size_t)arow_c * 64 + kk * 32 + g4 * 8);
#pragma unroll
        for (int t = 0; t < 4; ++t) {
            bf16x8 b = *(const bf16x8*)&sP[((kk * 4 + t) * 64 + lane) * 8];
            zac[t] = __builtin_amdgcn_mfma_f32_16x16x32_bf16(a, b, zac[t], 0, 0, 0);
        }
    }

#pragma unroll
    for (int r = 0; r < 4; ++r) {
        int row = row0 + g4 * 4 + r;
#pragma unroll
        for (int t = 0; t < 4; ++t) {
            float v = zac[t][r] + bp[t * 16 + r16];
            v = fmaxf(v, 0.f);
            zt[wv][g4 * 4 + r][t * 16 + r16] = f2bf(v);
            if (row < N_NODES)
                out[(size_t)Z_OFF + (size_t)row * 64 + t * 16 + r16] = v;
        }
    }
    __syncthreads();

    f32x4 lac = {0, 0, 0, 0};
#pragma unroll
    for (int kk = 0; kk < 2; ++kk) {
        bf16x8 a = *(const bf16x8*)&zt[wv][r16][kk * 32 + g4 * 8];
        bf16x8 b = *(const bf16x8*)&sC[(kk * 64 + lane) * 8];
        lac = __builtin_amdgcn_mfma_f32_16x16x32_bf16(a, b, lac, 0, 0, 0);
    }
#pragma unroll
    for (int r = 0; r < 4; ++r) {
        int row = row0 + g4 * 4 + r;
        if (row < N_NODES && r16 < NCLS)
            out[(size_t)row * NCLS + r16] = lac[r] + bc[r16];
    }
}

extern "C" void kernel_launch(void* const* d_in, const int* in_sizes, int n_in,
                              void* d_out, int out_size, void* d_ws, size_t ws_size,
                              hipStream_t stream) {
    const float* x  = (const float*)d_in[0];
    const int*   ei = (const int*)d_in[1];
    const float* W1 = (const float*)d_in[2];
    const float* b1 = (const float*)d_in[3];
    const float* W2 = (const float*)d_in[4];
    const float* b2 = (const float*)d_in[5];
    const float* Wp = (const float*)d_in[6];
    const float* bp = (const float*)d_in[7];
    const float* Wc = (const float*)d_in[8];
    const float* bc = (const float*)d_in[9];
    float* out = (float*)d_out;

    char* ws   = (char*)d_ws;
    int*  cnt  = (int*)(ws + OFF_CNT);
    int*  ovfc = (int*)(ws + OFF_OVFC);
    int*  ovf  = (int*)(ws + OFF_OVF);
    int*  col  = (int*)(ws + OFF_COL);
    u16*  wt   = (u16*)(ws + OFF_WT);
    u16*  g    = (u16*)(ws + OFF_G);
    u16*  h    = (u16*)(ws + OFF_H);

    k_wprep<<<100, 256, 0, stream>>>(W1, W2, Wp, Wc, wt, cnt);
    k_fill<<<(NE / 512) * NPART, 256, 0, stream>>>(ei, cnt, col, ovfc, ovf);
    k_gemm<IN_CH, false><<<GEMMB, 256, 0, stream>>>(x, wt + WT_W1, g);
    k_agg<<<N_NODES / 4, 256, 0, stream>>>(g, col, cnt, ovfc, ovf, b1, h);
    k_gemm<HID_D, true><<<GEMMB, 256, 0, stream>>>(h, wt + WT_W2, g);
    k_agg<<<N_NODES / 4, 256, 0, stream>>>(g, col, cnt, ovfc, ovf, b2, h);
    k_mlp<<<GEMMB, 256, 0, stream>>>(h, wt, bp, bc, out);
}

// Round 23
// 243.054 us; speedup vs baseline: 1.2341x; 1.2341x over previous
//
#include <hip/hip_runtime.h>

#define N_NODES 100000
#define IN_CH   256
#define HID_D   64
#define NCLS    6
#define NE      1600000
#define WB      48          // padded bucket width (Poisson(16) max deg ~42; ovf guard)
#define OVF_CAP 4096
#define NPART   8           // = #XCDs
#define PSZ     (N_NODES / NPART)   // 12500
#define GEMMB   1563                // ceil(N/64)

typedef unsigned short u16;
typedef unsigned int   u32;
typedef __attribute__((ext_vector_type(8))) short bf16x8;
typedef __attribute__((ext_vector_type(4))) float f32x4;
typedef __attribute__((ext_vector_type(2))) int   i32x2;

// ws layout (bytes)
#define OFF_CNT   0u                    // 100000*4 = 400000
#define OFF_OVFC  400000u               // 4
#define OFF_OVF   400128u               // -> 432896
#define OFF_COL   433152u               // 100000*48*4 -> 19,633,152
#define OFF_WT    19633152u             // 25600 u16 -> 19,684,352
#define OFF_G     19684480u             // G1 12.8MB -> 32,484,480
#define OFF_H     32484480u             // G2 12.8MB -> 45,284,480
// fragment-table element offsets (u16 units)
#define WT_W1 0
#define WT_W2 16384
#define WT_WP 20480
#define WT_WC 24576
#define WT_TOT 25600
#define Z_OFF 600000u                   // d_out f32: logits [0,600000), z rest

__device__ __forceinline__ u16 f2bf(float f) {
    u32 u = __float_as_uint(f);
    return (u16)((u + 0x7fffu + ((u >> 16) & 1u)) >> 16);   // RNE
}
__device__ __forceinline__ float bf2f(u16 h) {
    return __uint_as_float(((u32)h) << 16);
}

// ---- weights -> fragment tables; also zeroes cnt+ovfc ----
__global__ __launch_bounds__(256) void k_wprep(const float* __restrict__ W1,
                                               const float* __restrict__ W2,
                                               const float* __restrict__ Wp,
                                               const float* __restrict__ Wc,
                                               u16* __restrict__ wt,
                                               int* __restrict__ cntz) {
    int m = blockIdx.x * 256 + threadIdx.x;       // grid: 100 blocks
    for (int i = m; i <= N_NODES; i += 25600) cntz[i] = 0;   // cnt + ovfc
    if (m >= WT_TOT) return;
    float v;
    if (m >= WT_WC) {                             // Wc: [2][64][8], c = l&15
        int i = m - WT_WC;
        int j = i & 7, l = (i >> 3) & 63, kk = i >> 9;
        int k = kk * 32 + (l >> 4) * 8 + j;
        int c = l & 15;
        v = (c < NCLS) ? Wc[k * NCLS + c] : 0.f;
    } else {                                      // W1/W2/Wp: [KK][4][64][8]
        const float* src; int i;
        if      (m < WT_W2) { src = W1; i = m - WT_W1; }
        else if (m < WT_WP) { src = W2; i = m - WT_W2; }
        else                { src = Wp; i = m - WT_WP; }
        int j = i & 7, l = (i >> 3) & 63, t = (i >> 9) & 3, kk = i >> 11;
        int k = kk * 32 + (l >> 4) * 8 + j;
        int c = t * 16 + (l & 15);
        v = src[k * 64 + c];
    }
    wt[m] = f2bf(v);
}

// ---- XCD-partitioned bucket fill (R12/R17 proven body; atomicExch REVERTED:
// R22 showed atomics write through per-line -> WRITE 99.9MB, +66us) ----
__global__ __launch_bounds__(256) void k_fill(const int* __restrict__ ei,
                                              int* __restrict__ cnt,
                                              int* __restrict__ col,
                                              int* __restrict__ ovfc,
                                              int* __restrict__ ovf) {
    const int part = blockIdx.x & (NPART - 1);
    const int lo = part * PSZ;
    const int hi = lo + PSZ;
    const int e0 = (blockIdx.x >> 3) * 512 + threadIdx.x * 2;   // grid: (NE/512)*8
    i32x2 s2 = __builtin_nontemporal_load((const i32x2*)(ei + e0));
    i32x2 d2 = __builtin_nontemporal_load((const i32x2*)(ei + NE + e0));
#pragma unroll
    for (int j = 0; j < 2; ++j) {
        int s = s2[j];
        int d = d2[j];
        if (d < lo || d >= hi) continue;
        if ((u32)s >= (u32)N_NODES) continue;
        int p = atomicAdd(&cnt[d], 1);
        if (p < WB) {
            col[(size_t)d * WB + p] = s;
        } else {
            int k = atomicAdd(ovfc, 1);
            if (k < OVF_CAP) { ovf[2 * k] = s; ovf[2 * k + 1] = d; }
        }
    }
}

// ---- G1 = x @ W1 (bf16 out, UNSCALED; dinv in agg) ----
__global__ __launch_bounds__(256) void k_gemm1(const float* __restrict__ x,
                                               const u16* __restrict__ wt,
                                               u16* __restrict__ G) {
    __shared__ __align__(16) u16 sB[8 * 2048];
    for (int idx = threadIdx.x * 8; idx < 16384; idx += 2048)
        *(bf16x8*)&sB[idx] = *(const bf16x8*)&wt[idx];
    __syncthreads();

    const int lane = threadIdx.x & 63;
    const int wv   = threadIdx.x >> 6;
    const int row0 = blockIdx.x * 64 + wv * 16;
    const int g4   = lane >> 4;
    const int r16  = lane & 15;

    int arow = row0 + r16;
    int arow_c = arow < N_NODES ? arow : 0;

    f32x4 acc[4] = {{0,0,0,0},{0,0,0,0},{0,0,0,0},{0,0,0,0}};
#pragma unroll
    for (int kk = 0; kk < 8; ++kk) {
        const float* ap = x + (size_t)arow_c * IN_CH + kk * 32 + g4 * 8;
        float4 f0 = *(const float4*)ap;
        float4 f1 = *(const float4*)(ap + 4);
        bf16x8 a;
        a[0] = (short)f2bf(f0.x); a[1] = (short)f2bf(f0.y);
        a[2] = (short)f2bf(f0.z); a[3] = (short)f2bf(f0.w);
        a[4] = (short)f2bf(f1.x); a[5] = (short)f2bf(f1.y);
        a[6] = (short)f2bf(f1.z); a[7] = (short)f2bf(f1.w);
#pragma unroll
        for (int t = 0; t < 4; ++t) {
            bf16x8 b = *(const bf16x8*)&sB[((kk * 4 + t) * 64 + lane) * 8];
            acc[t] = __builtin_amdgcn_mfma_f32_16x16x32_bf16(a, b, acc[t], 0, 0, 0);
        }
    }
#pragma unroll
    for (int r = 0; r < 4; ++r) {
        int row = row0 + g4 * 4 + r;
        if (row < N_NODES)
#pragma unroll
            for (int t = 0; t < 4; ++t)
                G[(size_t)row * 64 + t * 16 + r16] = f2bf(acc[t][r]);
    }
}

// ---- shared agg body: one node -> bf16 H value per lane (G unscaled) ----
__device__ __forceinline__ u16 agg_node(int node,
                                        const u16* __restrict__ G,
                                        const int* __restrict__ col,
                                        const int* __restrict__ cnt,
                                        const int* __restrict__ ovfc,
                                        const int* __restrict__ ovf,
                                        const float* __restrict__ bias,
                                        int lane) {
    int deg = cnt[node];
    int m = min(deg, WB);
    float dinv_i = rsqrtf((float)(deg + 1));

    int mycol = (lane < m) ? col[(size_t)node * WB + lane] : 0;
    float mydinv = rsqrtf((float)(cnt[mycol] + 1));

    float acc = dinv_i * bf2f(G[(size_t)node * 64 + lane]);      // self term

    int e = 0;
    for (; e + 4 <= m; e += 4) {
        int c0 = __shfl(mycol, e + 0), c1 = __shfl(mycol, e + 1);
        int c2 = __shfl(mycol, e + 2), c3 = __shfl(mycol, e + 3);
        float w0 = __shfl(mydinv, e + 0), w1 = __shfl(mydinv, e + 1);
        float w2 = __shfl(mydinv, e + 2), w3 = __shfl(mydinv, e + 3);
        acc += w0 * bf2f(G[(size_t)c0 * 64 + lane]);
        acc += w1 * bf2f(G[(size_t)c1 * 64 + lane]);
        acc += w2 * bf2f(G[(size_t)c2 * 64 + lane]);
        acc += w3 * bf2f(G[(size_t)c3 * 64 + lane]);
    }
    for (; e < m; ++e) {
        int c = __shfl(mycol, e);
        float w = __shfl(mydinv, e);
        acc += w * bf2f(G[(size_t)c * 64 + lane]);
    }

    int no = *ovfc;
    if (no > 0) {                        // ~never taken (deg > 48)
        no = min(no, OVF_CAP);
        for (int j = 0; j < no; ++j)
            if (ovf[2 * j + 1] == node) {
                int s = ovf[2 * j];
                acc += rsqrtf((float)(cnt[s] + 1)) * bf2f(G[(size_t)s * 64 + lane]);
            }
    }
    return f2bf(fmaxf(dinv_i * acc + bias[lane], 0.f));
}

// ---- FUSED agg1 + gemm2: 64-node tile. 16 waves x 4 nodes -> H1 tile in LDS,
// then 16x 16x16 MFMA tiles -> G2 (unscaled) to the h buffer. Dependency is
// row-block local, so no grid sync needed. ----
__global__ __launch_bounds__(1024) void k_aggemm2(const u16* __restrict__ G,
                                                  const int* __restrict__ col,
                                                  const int* __restrict__ cnt,
                                                  const int* __restrict__ ovfc,
                                                  const int* __restrict__ ovf,
                                                  const float* __restrict__ b1,
                                                  const u16* __restrict__ wtW2,
                                                  u16* __restrict__ G2) {
    __shared__ __align__(16) u16 sH[64][72];   // +8 pad: 144B row stride, 2-way banks
    __shared__ __align__(16) u16 sB[4096];

    const int tid = threadIdx.x;
    const int w    = tid >> 6;
    const int lane = tid & 63;
    {
        int idx = tid * 8;
        if (idx < 4096) *(bf16x8*)&sB[idx] = *(const bf16x8*)&wtW2[idx];
    }

    const int base = blockIdx.x * 64;
#pragma unroll
    for (int q = 0; q < 4; ++q) {
        int node = base + w * 4 + q;
        sH[w * 4 + q][lane] = (node < N_NODES)
            ? agg_node(node, G, col, cnt, ovfc, ovf, b1, lane) : (u16)0;
    }
    __syncthreads();

    const int r0 = (w >> 2) * 16;      // row tile
    const int c0 = (w & 3) * 16;       // col tile
    const int g4 = lane >> 4;
    const int r16 = lane & 15;

    f32x4 acc = {0, 0, 0, 0};
#pragma unroll
    for (int kk = 0; kk < 2; ++kk) {
        bf16x8 a = *(const bf16x8*)&sH[r0 + r16][kk * 32 + g4 * 8];
        bf16x8 b = *(const bf16x8*)&sB[((kk * 4 + (w & 3)) * 64 + lane) * 8];
        acc = __builtin_amdgcn_mfma_f32_16x16x32_bf16(a, b, acc, 0, 0, 0);
    }
#pragma unroll
    for (int r = 0; r < 4; ++r) {
        int row = base + r0 + g4 * 4 + r;
        if (row < N_NODES)
            G2[(size_t)row * 64 + c0 + r16] = f2bf(acc[r]);
    }
}

// ---- FUSED agg2 + mlp: H2 tile in LDS -> z (relu, ->out f32 + LDS bf16)
// -> logits via Wc MFMA (waves 0-3) ----
__global__ __launch_bounds__(1024) void k_aggmlp(const u16* __restrict__ G2,
                                                 const int* __restrict__ col,
                                                 const int* __restrict__ cnt,
                                                 const int* __restrict__ ovfc,
                                                 const int* __restrict__ ovf,
                                                 const float* __restrict__ b2,
                                                 const u16* __restrict__ wt,
                                                 const float* __restrict__ bp,
                                                 const float* __restrict__ bc,
                                                 float* __restrict__ out) {
    __shared__ __align__(16) u16 sH[64][72];
    __shared__ __align__(16) u16 sZ[64][72];
    __shared__ __align__(16) u16 sP[4096];
    __shared__ __align__(16) u16 sC[1024];

    const int tid = threadIdx.x;
    const int w    = tid >> 6;
    const int lane = tid & 63;
    {
        int idx = tid * 8;
        if (idx < 4096) *(bf16x8*)&sP[idx] = *(const bf16x8*)&wt[WT_WP + idx];
        if (idx < 1024) *(bf16x8*)&sC[idx] = *(const bf16x8*)&wt[WT_WC + idx];
    }

    const int base = blockIdx.x * 64;
#pragma unroll
    for (int q = 0; q < 4; ++q) {
        int node = base + w * 4 + q;
        sH[w * 4 + q][lane] = (node < N_NODES)
            ? agg_node(node, G2, col, cnt, ovfc, ovf, b2, lane) : (u16)0;
    }
    __syncthreads();

    const int r0 = (w >> 2) * 16;
    const int c0 = (w & 3) * 16;
    const int g4 = lane >> 4;
    const int r16 = lane & 15;

    // z = relu(H2 @ Wp + bp)
    f32x4 zac = {0, 0, 0, 0};
#pragma unroll
    for (int kk = 0; kk < 2; ++kk) {
        bf16x8 a = *(const bf16x8*)&sH[r0 + r16][kk * 32 + g4 * 8];
        bf16x8 b = *(const bf16x8*)&sP[((kk * 4 + (w & 3)) * 64 + lane) * 8];
        zac = __builtin_amdgcn_mfma_f32_16x16x32_bf16(a, b, zac, 0, 0, 0);
    }
#pragma unroll
    for (int r = 0; r < 4; ++r) {
        int row = base + r0 + g4 * 4 + r;
        float v = fmaxf(zac[r] + bp[c0 + r16], 0.f);
        sZ[r0 + g4 * 4 + r][c0 + r16] = f2bf(v);
        if (row < N_NODES)
            out[(size_t)Z_OFF + (size_t)row * 64 + c0 + r16] = v;
    }
    __syncthreads();

    // logits = z @ Wc + bc  (waves 0-3; 64x16-padded output)
    if (w < 4) {
        const int lr0 = w * 16;
        f32x4 lac = {0, 0, 0, 0};
#pragma unroll
        for (int kk = 0; kk < 2; ++kk) {
            bf16x8 a = *(const bf16x8*)&sZ[lr0 + r16][kk * 32 + g4 * 8];
            bf16x8 b = *(const bf16x8*)&sC[(kk * 64 + lane) * 8];
            lac = __builtin_amdgcn_mfma_f32_16x16x32_bf16(a, b, lac, 0, 0, 0);
        }
#pragma unroll
        for (int r = 0; r < 4; ++r) {
            int row = base + lr0 + g4 * 4 + r;
            if (row < N_NODES && r16 < NCLS)
                out[(size_t)row * NCLS + r16] = lac[r] + bc[r16];
        }
    }
}

extern "C" void kernel_launch(void* const* d_in, const int* in_sizes, int n_in,
                              void* d_out, int out_size, void* d_ws, size_t ws_size,
                              hipStream_t stream) {
    const float* x  = (const float*)d_in[0];
    const int*   ei = (const int*)d_in[1];
    const float* W1 = (const float*)d_in[2];
    const float* b1 = (const float*)d_in[3];
    const float* W2 = (const float*)d_in[4];
    const float* b2 = (const float*)d_in[5];
    const float* Wp = (const float*)d_in[6];
    const float* bp = (const float*)d_in[7];
    const float* Wc = (const float*)d_in[8];
    const float* bc = (const float*)d_in[9];
    float* out = (float*)d_out;

    char* ws   = (char*)d_ws;
    int*  cnt  = (int*)(ws + OFF_CNT);
    int*  ovfc = (int*)(ws + OFF_OVFC);
    int*  ovf  = (int*)(ws + OFF_OVF);
    int*  col  = (int*)(ws + OFF_COL);
    u16*  wt   = (u16*)(ws + OFF_WT);
    u16*  g    = (u16*)(ws + OFF_G);
    u16*  g2   = (u16*)(ws + OFF_H);

    k_wprep<<<100, 256, 0, stream>>>(W1, W2, Wp, Wc, wt, cnt);
    k_fill<<<(NE / 512) * NPART, 256, 0, stream>>>(ei, cnt, col, ovfc, ovf);
    k_gemm1<<<GEMMB, 256, 0, stream>>>(x, wt + WT_W1, g);
    k_aggemm2<<<GEMMB, 1024, 0, stream>>>(g, col, cnt, ovfc, ovf, b1, wt + WT_W2, g2);
    k_aggmlp<<<GEMMB, 1024, 0, stream>>>(g2, col, cnt, ovfc, ovf, b2, wt, bp, bc, out);
}

// Round 24
// 218.558 us; speedup vs baseline: 1.3724x; 1.1121x over previous
//
#include <hip/hip_runtime.h>

#define N_NODES 100000
#define IN_CH   256
#define HID_D   64
#define NCLS    6
#define NE      1600000
#define WB      48          // padded bucket width (Poisson(16) max deg ~42; ovf guard)
#define OVF_CAP 4096
#define NPART   8           // = #XCDs
#define PSZ     (N_NODES / NPART)   // 12500
#define GEMMB   1563                // ceil(N/64)

typedef unsigned short u16;
typedef unsigned int   u32;
typedef __attribute__((ext_vector_type(8))) short bf16x8;
typedef __attribute__((ext_vector_type(4))) float f32x4;
typedef __attribute__((ext_vector_type(2))) int   i32x2;

// ws layout (bytes)
#define OFF_CNT   0u                    // 100000*4 = 400000
#define OFF_OVFC  400000u               // 4
#define OFF_OVF   400128u               // -> 432896
#define OFF_COL   433152u               // 100000*48*4 -> 19,633,152
#define OFF_WT    19633152u             // 25600 u16 -> 19,684,352
#define OFF_G     19684480u             // 12.8MB bf16 -> 32,484,480
#define OFF_H     32484480u             // 12.8MB bf16 -> 45,284,480
// fragment-table element offsets (u16 units)
#define WT_W1 0
#define WT_W2 16384
#define WT_WP 20480
#define WT_WC 24576
#define WT_TOT 25600
#define Z_OFF 600000u                   // d_out f32: logits [0,600000), z rest

__device__ __forceinline__ u16 f2bf(float f) {
    u32 u = __float_as_uint(f);
    return (u16)((u + 0x7fffu + ((u >> 16) & 1u)) >> 16);   // RNE
}
__device__ __forceinline__ float bf2f(u16 h) {
    return __uint_as_float(((u32)h) << 16);
}

// ---- weights -> fragment tables; also zeroes cnt+ovfc (no memset dispatch) ----
__global__ __launch_bounds__(256) void k_wprep(const float* __restrict__ W1,
                                               const float* __restrict__ W2,
                                               const float* __restrict__ Wp,
                                               const float* __restrict__ Wc,
                                               u16* __restrict__ wt,
                                               int* __restrict__ cntz) {
    int m = blockIdx.x * 256 + threadIdx.x;       // grid exact: 100 blocks
    for (int i = m; i <= N_NODES; i += 25600) cntz[i] = 0;   // cnt + ovfc
    if (m >= WT_TOT) return;
    float v;
    if (m >= WT_WC) {                             // Wc: [2][64][8], c = l&15
        int i = m - WT_WC;
        int j = i & 7, l = (i >> 3) & 63, kk = i >> 9;
        int k = kk * 32 + (l >> 4) * 8 + j;
        int c = l & 15;
        v = (c < NCLS) ? Wc[k * NCLS + c] : 0.f;
    } else {                                      // W1/W2/Wp: [KK][4][64][8]
        const float* src; int i;
        if      (m < WT_W2) { src = W1; i = m - WT_W1; }
        else if (m < WT_WP) { src = W2; i = m - WT_W2; }
        else                { src = Wp; i = m - WT_WP; }
        int j = i & 7, l = (i >> 3) & 63, t = (i >> 9) & 3, kk = i >> 11;
        int k = kk * 32 + (l >> 4) * 8 + j;
        int c = t * 16 + (l & 15);
        v = src[k * 64 + c];
    }
    wt[m] = f2bf(v);
}

// ---- XCD-partitioned bucket fill (R12/R17 proven body) ----
__global__ __launch_bounds__(256) void k_fill(const int* __restrict__ ei,
                                              int* __restrict__ cnt,
                                              int* __restrict__ col,
                                              int* __restrict__ ovfc,
                                              int* __restrict__ ovf) {
    const int part = blockIdx.x & (NPART - 1);
    const int lo = part * PSZ;
    const int hi = lo + PSZ;
    const int e0 = (blockIdx.x >> 3) * 512 + threadIdx.x * 2;   // grid: (NE/512)*8
    i32x2 s2 = __builtin_nontemporal_load((const i32x2*)(ei + e0));
    i32x2 d2 = __builtin_nontemporal_load((const i32x2*)(ei + NE + e0));
#pragma unroll
    for (int j = 0; j < 2; ++j) {
        int s = s2[j];
        int d = d2[j];
        if (d < lo || d >= hi) continue;
        if ((u32)s >= (u32)N_NODES) continue;
        int p = atomicAdd(&cnt[d], 1);
        if (p < WB) {
            col[(size_t)d * WB + p] = s;
        } else {
            int k = atomicAdd(ovfc, 1);
            if (k < OVF_CAP) { ovf[2 * k] = s; ovf[2 * k + 1] = d; }
        }
    }
}

// ---- G(bf16) = dinv .* (A @ W); staging from pre-built fragment table ----
template <int KDIM, bool ABF16>
__global__ __launch_bounds__(256) void k_gemm(const void* __restrict__ A,
                                              const u16* __restrict__ wt,
                                              const int* __restrict__ cnt,
                                              u16* __restrict__ G) {
    constexpr int KK = KDIM / 32;
    __shared__ __align__(16) u16 sB[KK * 2048];

    for (int idx = threadIdx.x * 8; idx < KK * 2048; idx += 2048)
        *(bf16x8*)&sB[idx] = *(const bf16x8*)&wt[idx];   // linear coalesced
    __syncthreads();

    const int lane = threadIdx.x & 63;
    const int wv   = threadIdx.x >> 6;
    const int row0 = blockIdx.x * 64 + wv * 16;
    const int g4   = lane >> 4;
    const int r16  = lane & 15;

    int arow = row0 + r16;
    int arow_c = arow < N_NODES ? arow : 0;

    f32x4 acc[4] = {{0,0,0,0},{0,0,0,0},{0,0,0,0},{0,0,0,0}};

#pragma unroll
    for (int kk = 0; kk < KK; ++kk) {
        bf16x8 a;
        if (ABF16) {
            a = *(const bf16x8*)((const u16*)A + (size_t)arow_c * KDIM + kk * 32 + g4 * 8);
        } else {
            const float* ap = (const float*)A + (size_t)arow_c * KDIM + kk * 32 + g4 * 8;
            float4 f0 = *(const float4*)ap;
            float4 f1 = *(const float4*)(ap + 4);
            a[0] = (short)f2bf(f0.x); a[1] = (short)f2bf(f0.y);
            a[2] = (short)f2bf(f0.z); a[3] = (short)f2bf(f0.w);
            a[4] = (short)f2bf(f1.x); a[5] = (short)f2bf(f1.y);
            a[6] = (short)f2bf(f1.z); a[7] = (short)f2bf(f1.w);
        }
#pragma unroll
        for (int t = 0; t < 4; ++t) {
            bf16x8 b = *(const bf16x8*)&sB[((kk * 4 + t) * 64 + lane) * 8];
            acc[t] = __builtin_amdgcn_mfma_f32_16x16x32_bf16(a, b, acc[t], 0, 0, 0);
        }
    }

#pragma unroll
    for (int r = 0; r < 4; ++r) {
        int row = row0 + g4 * 4 + r;
        if (row < N_NODES) {
            float dinv = rsqrtf((float)(cnt[row] + 1));
#pragma unroll
            for (int t = 0; t < 4; ++t)
                G[(size_t)row * 64 + t * 16 + r16] = f2bf(acc[t][r] * dinv);
        }
    }
}

// ---- Hout(bf16) = relu(dinv[i]*(g[i] + sum_{e:dst=i} g[src_e]) + bias) ----
__global__ __launch_bounds__(256) void k_agg(const u16* __restrict__ G,
                                             const int* __restrict__ col,
                                             const int* __restrict__ cnt,
                                             const int* __restrict__ ovfc,
                                             const int* __restrict__ ovf,
                                             const float* __restrict__ bias,
                                             u16* __restrict__ Hout) {
    int node = blockIdx.x * 4 + (threadIdx.x >> 6);   // grid exact: N/4
    int lane = threadIdx.x & 63;

    int deg = cnt[node];
    int m = min(deg, WB);
    int mycol = (lane < WB) ? col[(size_t)node * WB + lane] : 0;

    float acc = bf2f(G[(size_t)node * 64 + lane]);    // self loop

    int e = 0;
    for (; e + 4 <= m; e += 4) {
        int c0 = __shfl(mycol, e + 0), c1 = __shfl(mycol, e + 1);
        int c2 = __shfl(mycol, e + 2), c3 = __shfl(mycol, e + 3);
        float v0 = bf2f(G[(size_t)c0 * 64 + lane]);
        float v1 = bf2f(G[(size_t)c1 * 64 + lane]);
        float v2 = bf2f(G[(size_t)c2 * 64 + lane]);
        float v3 = bf2f(G[(size_t)c3 * 64 + lane]);
        acc += v0; acc += v1; acc += v2; acc += v3;
    }
    for (; e < m; ++e) {
        int c = __shfl(mycol, e);
        acc += bf2f(G[(size_t)c * 64 + lane]);
    }

    int no = *ovfc;
    if (no > 0) {                        // ~never taken (deg > 48)
        no = min(no, OVF_CAP);
        for (int j = 0; j < no; ++j)
            if (ovf[2 * j + 1] == node)
                acc += bf2f(G[(size_t)ovf[2 * j] * 64 + lane]);
    }

    float dinv = rsqrtf((float)(deg + 1));
    float v = fmaxf(acc * dinv + bias[lane], 0.f);
    Hout[(size_t)node * 64 + lane] = f2bf(v);
}

// ---- z = relu(H@Wp+bp) -> out f32 [Z_OFF..]; logits = z@Wc+bc -> out f32 ----
__global__ __launch_bounds__(256) void k_mlp(const u16* __restrict__ H,
                                             const u16* __restrict__ wt,
                                             const float* __restrict__ bp,
                                             const float* __restrict__ bc,
                                             float* __restrict__ out) {
    __shared__ __align__(16) u16 sP[2 * 2048];
    __shared__ __align__(16) u16 sC[1024];
    __shared__ __align__(16) u16 zt[4][16][72];

    for (int idx = threadIdx.x * 8; idx < 4096; idx += 2048)
        *(bf16x8*)&sP[idx] = *(const bf16x8*)&wt[WT_WP + idx];
    {
        int idx = threadIdx.x * 8;
        if (idx < 1024)
            *(bf16x8*)&sC[idx] = *(const bf16x8*)&wt[WT_WC + idx];
    }
    __syncthreads();

    const int lane = threadIdx.x & 63;
    const int wv   = threadIdx.x >> 6;
    const int row0 = blockIdx.x * 64 + wv * 16;
    const int g4   = lane >> 4;
    const int r16  = lane & 15;

    int arow = row0 + r16;
    int arow_c = arow < N_NODES ? arow : (N_NODES - 1);

    f32x4 zac[4] = {{0,0,0,0},{0,0,0,0},{0,0,0,0},{0,0,0,0}};
#pragma unroll
    for (int kk = 0; kk < 2; ++kk) {
        bf16x8 a = *(const bf16x8*)((const u16*)H + (size_t)arow_c * 64 + kk * 32 + g4 * 8);
#pragma unroll
        for (int t = 0; t < 4; ++t) {
            bf16x8 b = *(const bf16x8*)&sP[((kk * 4 + t) * 64 + lane) * 8];
            zac[t] = __builtin_amdgcn_mfma_f32_16x16x32_bf16(a, b, zac[t], 0, 0, 0);
        }
    }

#pragma unroll
    for (int r = 0; r < 4; ++r) {
        int row = row0 + g4 * 4 + r;
#pragma unroll
        for (int t = 0; t < 4; ++t) {
            float v = zac[t][r] + bp[t * 16 + r16];
            v = fmaxf(v, 0.f);
            zt[wv][g4 * 4 + r][t * 16 + r16] = f2bf(v);
            if (row < N_NODES)
                out[(size_t)Z_OFF + (size_t)row * 64 + t * 16 + r16] = v;
        }
    }
    __syncthreads();

    f32x4 lac = {0, 0, 0, 0};
#pragma unroll
    for (int kk = 0; kk < 2; ++kk) {
        bf16x8 a = *(const bf16x8*)&zt[wv][r16][kk * 32 + g4 * 8];
        bf16x8 b = *(const bf16x8*)&sC[(kk * 64 + lane) * 8];
        lac = __builtin_amdgcn_mfma_f32_16x16x32_bf16(a, b, lac, 0, 0, 0);
    }
#pragma unroll
    for (int r = 0; r < 4; ++r) {
        int row = row0 + g4 * 4 + r;
        if (row < N_NODES && r16 < NCLS)
            out[(size_t)row * NCLS + r16] = lac[r] + bc[r16];
    }
}

extern "C" void kernel_launch(void* const* d_in, const int* in_sizes, int n_in,
                              void* d_out, int out_size, void* d_ws, size_t ws_size,
                              hipStream_t stream) {
    const float* x  = (const float*)d_in[0];
    const int*   ei = (const int*)d_in[1];
    const float* W1 = (const float*)d_in[2];
    const float* b1 = (const float*)d_in[3];
    const float* W2 = (const float*)d_in[4];
    const float* b2 = (const float*)d_in[5];
    const float* Wp = (const float*)d_in[6];
    const float* bp = (const float*)d_in[7];
    const float* Wc = (const float*)d_in[8];
    const float* bc = (const float*)d_in[9];
    float* out = (float*)d_out;

    char* ws   = (char*)d_ws;
    int*  cnt  = (int*)(ws + OFF_CNT);
    int*  ovfc = (int*)(ws + OFF_OVFC);
    int*  ovf  = (int*)(ws + OFF_OVF);
    int*  col  = (int*)(ws + OFF_COL);
    u16*  wt   = (u16*)(ws + OFF_WT);
    u16*  g    = (u16*)(ws + OFF_G);
    u16*  h    = (u16*)(ws + OFF_H);

    k_wprep<<<100, 256, 0, stream>>>(W1, W2, Wp, Wc, wt, cnt);
    k_fill<<<(NE / 512) * NPART, 256, 0, stream>>>(ei, cnt, col, ovfc, ovf);
    k_gemm<IN_CH, false><<<GEMMB, 256, 0, stream>>>(x, wt + WT_W1, cnt, g);
    k_agg<<<N_NODES / 4, 256, 0, stream>>>(g, col, cnt, ovfc, ovf, b1, h);
    k_gemm<HID_D, true><<<GEMMB, 256, 0, stream>>>(h, wt + WT_W2, cnt, g);
    k_agg<<<N_NODES / 4, 256, 0, stream>>>(g, col, cnt, ovfc, ovf, b2, h);
    k_mlp<<<GEMMB, 256, 0, stream>>>(h, wt, bp, bc, out);
}

// Round 25
// 208.284 us; speedup vs baseline: 1.4401x; 1.0493x over previous
//
#include <hip/hip_runtime.h>

#define N_NODES 100000
#define IN_CH   256
#define HID_D   64
#define NCLS    6
#define NE      1600000
#define WB      48          // padded bucket width (Poisson(16) max deg ~42; ovf guard)
#define OVF_CAP 4096
#define NPART   8           // = #XCDs
#define PSZ     (N_NODES / NPART)   // 12500
#define GEMMB   1563                // ceil(N/64)

typedef unsigned short u16;
typedef unsigned int   u32;
typedef __attribute__((ext_vector_type(8))) short bf16x8;
typedef __attribute__((ext_vector_type(4))) float f32x4;
typedef __attribute__((ext_vector_type(2))) int   i32x2;

// ws layout (bytes)
#define OFF_CNT   0u                    // 100000*4 = 400000
#define OFF_OVFC  400000u               // 4
#define OFF_OVF   400128u               // -> 432896
#define OFF_COL   433152u               // 100000*48*4 -> 19,633,152
#define OFF_WT    19633152u             // 25600 u16 -> 19,684,352
#define OFF_G     19684480u             // 12.8MB bf16 -> 32,484,480
#define OFF_H     32484480u             // 12.8MB bf16 -> 45,284,480
// fragment-table element offsets (u16 units)
#define WT_W1 0
#define WT_W2 16384
#define WT_WP 20480
#define WT_WC 24576
#define WT_TOT 25600
#define Z_OFF 600000u                   // d_out f32: logits [0,600000), z rest

__device__ __forceinline__ u16 f2bf(float f) {
    u32 u = __float_as_uint(f);
    return (u16)((u + 0x7fffu + ((u >> 16) & 1u)) >> 16);   // RNE
}
__device__ __forceinline__ float bf2f(u16 h) {
    return __uint_as_float(((u32)h) << 16);
}

// ---- weights -> fragment tables; also zeroes cnt+ovfc (no memset dispatch) ----
__global__ __launch_bounds__(256) void k_wprep(const float* __restrict__ W1,
                                               const float* __restrict__ W2,
                                               const float* __restrict__ Wp,
                                               const float* __restrict__ Wc,
                                               u16* __restrict__ wt,
                                               int* __restrict__ cntz) {
    int m = blockIdx.x * 256 + threadIdx.x;       // grid exact: 100 blocks
    for (int i = m; i <= N_NODES; i += 25600) cntz[i] = 0;   // cnt + ovfc
    if (m >= WT_TOT) return;
    float v;
    if (m >= WT_WC) {                             // Wc: [2][64][8], c = l&15
        int i = m - WT_WC;
        int j = i & 7, l = (i >> 3) & 63, kk = i >> 9;
        int k = kk * 32 + (l >> 4) * 8 + j;
        int c = l & 15;
        v = (c < NCLS) ? Wc[k * NCLS + c] : 0.f;
    } else {                                      // W1/W2/Wp: [KK][4][64][8]
        const float* src; int i;
        if      (m < WT_W2) { src = W1; i = m - WT_W1; }
        else if (m < WT_WP) { src = W2; i = m - WT_W2; }
        else                { src = Wp; i = m - WT_WP; }
        int j = i & 7, l = (i >> 3) & 63, t = (i >> 9) & 3, kk = i >> 11;
        int k = kk * 32 + (l >> 4) * 8 + j;
        int c = t * 16 + (l & 15);
        v = src[k * 64 + c];
    }
    wt[m] = f2bf(v);
}

// ---- XCD-partitioned bucket fill (R12/R17 proven body) ----
__global__ __launch_bounds__(256) void k_fill(const int* __restrict__ ei,
                                              int* __restrict__ cnt,
                                              int* __restrict__ col,
                                              int* __restrict__ ovfc,
                                              int* __restrict__ ovf) {
    const int part = blockIdx.x & (NPART - 1);
    const int lo = part * PSZ;
    const int hi = lo + PSZ;
    const int e0 = (blockIdx.x >> 3) * 512 + threadIdx.x * 2;   // grid: (NE/512)*8
    i32x2 s2 = __builtin_nontemporal_load((const i32x2*)(ei + e0));
    i32x2 d2 = __builtin_nontemporal_load((const i32x2*)(ei + NE + e0));
#pragma unroll
    for (int j = 0; j < 2; ++j) {
        int s = s2[j];
        int d = d2[j];
        if (d < lo || d >= hi) continue;
        if ((u32)s >= (u32)N_NODES) continue;
        int p = atomicAdd(&cnt[d], 1);
        if (p < WB) {
            col[(size_t)d * WB + p] = s;
        } else {
            int k = atomicAdd(ovfc, 1);
            if (k < OVF_CAP) { ovf[2 * k] = s; ovf[2 * k + 1] = d; }
        }
    }
}

// ---- G(bf16) = dinv .* (A @ W); staging from pre-built fragment table ----
template <int KDIM, bool ABF16>
__global__ __launch_bounds__(256) void k_gemm(const void* __restrict__ A,
                                              const u16* __restrict__ wt,
                                              const int* __restrict__ cnt,
                                              u16* __restrict__ G) {
    constexpr int KK = KDIM / 32;
    __shared__ __align__(16) u16 sB[KK * 2048];

    for (int idx = threadIdx.x * 8; idx < KK * 2048; idx += 2048)
        *(bf16x8*)&sB[idx] = *(const bf16x8*)&wt[idx];   // linear coalesced
    __syncthreads();

    const int lane = threadIdx.x & 63;
    const int wv   = threadIdx.x >> 6;
    const int row0 = blockIdx.x * 64 + wv * 16;
    const int g4   = lane >> 4;
    const int r16  = lane & 15;

    int arow = row0 + r16;
    int arow_c = arow < N_NODES ? arow : 0;

    f32x4 acc[4] = {{0,0,0,0},{0,0,0,0},{0,0,0,0},{0,0,0,0}};

#pragma unroll
    for (int kk = 0; kk < KK; ++kk) {
        bf16x8 a;
        if (ABF16) {
            a = *(const bf16x8*)((const u16*)A + (size_t)arow_c * KDIM + kk * 32 + g4 * 8);
        } else {
            const float* ap = (const float*)A + (size_t)arow_c * KDIM + kk * 32 + g4 * 8;
            float4 f0 = *(const float4*)ap;
            float4 f1 = *(const float4*)(ap + 4);
            a[0] = (short)f2bf(f0.x); a[1] = (short)f2bf(f0.y);
            a[2] = (short)f2bf(f0.z); a[3] = (short)f2bf(f0.w);
            a[4] = (short)f2bf(f1.x); a[5] = (short)f2bf(f1.y);
            a[6] = (short)f2bf(f1.z); a[7] = (short)f2bf(f1.w);
        }
#pragma unroll
        for (int t = 0; t < 4; ++t) {
            bf16x8 b = *(const bf16x8*)&sB[((kk * 4 + t) * 64 + lane) * 8];
            acc[t] = __builtin_amdgcn_mfma_f32_16x16x32_bf16(a, b, acc[t], 0, 0, 0);
        }
    }

#pragma unroll
    for (int r = 0; r < 4; ++r) {
        int row = row0 + g4 * 4 + r;
        if (row < N_NODES) {
            float dinv = rsqrtf((float)(cnt[row] + 1));
#pragma unroll
            for (int t = 0; t < 4; ++t)
                G[(size_t)row * 64 + t * 16 + r16] = f2bf(acc[t][r] * dinv);
        }
    }
}

// ---- Hout(bf16) = relu(dinv[i]*(g[i] + sum_{e:dst=i} g[src_e]) + bias) ----
// R25: 8-wide gather batches (was 4) -- halves the dependent-round count of
// the per-wave edge walk (avg deg 16 -> 2-3 rounds instead of 4-5).
__global__ __launch_bounds__(256) void k_agg(const u16* __restrict__ G,
                                             const int* __restrict__ col,
                                             const int* __restrict__ cnt,
                                             const int* __restrict__ ovfc,
                                             const int* __restrict__ ovf,
                                             const float* __restrict__ bias,
                                             u16* __restrict__ Hout) {
    int node = blockIdx.x * 4 + (threadIdx.x >> 6);   // grid exact: N/4
    int lane = threadIdx.x & 63;

    int deg = cnt[node];
    int m = min(deg, WB);
    int mycol = (lane < WB) ? col[(size_t)node * WB + lane] : 0;

    float acc = bf2f(G[(size_t)node * 64 + lane]);    // self loop

    int e = 0;
    for (; e + 8 <= m; e += 8) {
        int c0 = __shfl(mycol, e + 0), c1 = __shfl(mycol, e + 1);
        int c2 = __shfl(mycol, e + 2), c3 = __shfl(mycol, e + 3);
        int c4 = __shfl(mycol, e + 4), c5 = __shfl(mycol, e + 5);
        int c6 = __shfl(mycol, e + 6), c7 = __shfl(mycol, e + 7);
        float v0 = bf2f(G[(size_t)c0 * 64 + lane]);
        float v1 = bf2f(G[(size_t)c1 * 64 + lane]);
        float v2 = bf2f(G[(size_t)c2 * 64 + lane]);
        float v3 = bf2f(G[(size_t)c3 * 64 + lane]);
        float v4 = bf2f(G[(size_t)c4 * 64 + lane]);
        float v5 = bf2f(G[(size_t)c5 * 64 + lane]);
        float v6 = bf2f(G[(size_t)c6 * 64 + lane]);
        float v7 = bf2f(G[(size_t)c7 * 64 + lane]);
        acc += v0; acc += v1; acc += v2; acc += v3;
        acc += v4; acc += v5; acc += v6; acc += v7;
    }
    if (e + 4 <= m) {
        int c0 = __shfl(mycol, e + 0), c1 = __shfl(mycol, e + 1);
        int c2 = __shfl(mycol, e + 2), c3 = __shfl(mycol, e + 3);
        float v0 = bf2f(G[(size_t)c0 * 64 + lane]);
        float v1 = bf2f(G[(size_t)c1 * 64 + lane]);
        float v2 = bf2f(G[(size_t)c2 * 64 + lane]);
        float v3 = bf2f(G[(size_t)c3 * 64 + lane]);
        acc += v0; acc += v1; acc += v2; acc += v3;
        e += 4;
    }
    for (; e < m; ++e) {
        int c = __shfl(mycol, e);
        acc += bf2f(G[(size_t)c * 64 + lane]);
    }

    int no = *ovfc;
    if (no > 0) {                        // ~never taken (deg > 48)
        no = min(no, OVF_CAP);
        for (int j = 0; j < no; ++j)
            if (ovf[2 * j + 1] == node)
                acc += bf2f(G[(size_t)ovf[2 * j] * 64 + lane]);
    }

    float dinv = rsqrtf((float)(deg + 1));
    float v = fmaxf(acc * dinv + bias[lane], 0.f);
    Hout[(size_t)node * 64 + lane] = f2bf(v);
}

// ---- z = relu(H@Wp+bp) -> out f32 [Z_OFF..]; logits = z@Wc+bc -> out f32 ----
__global__ __launch_bounds__(256) void k_mlp(const u16* __restrict__ H,
                                             const u16* __restrict__ wt,
                                             const float* __restrict__ bp,
                                             const float* __restrict__ bc,
                                             float* __restrict__ out) {
    __shared__ __align__(16) u16 sP[2 * 2048];
    __shared__ __align__(16) u16 sC[1024];
    __shared__ __align__(16) u16 zt[4][16][72];

    for (int idx = threadIdx.x * 8; idx < 4096; idx += 2048)
        *(bf16x8*)&sP[idx] = *(const bf16x8*)&wt[WT_WP + idx];
    {
        int idx = threadIdx.x * 8;
        if (idx < 1024)
            *(bf16x8*)&sC[idx] = *(const bf16x8*)&wt[WT_WC + idx];
    }
    __syncthreads();

    const int lane = threadIdx.x & 63;
    const int wv   = threadIdx.x >> 6;
    const int row0 = blockIdx.x * 64 + wv * 16;
    const int g4   = lane >> 4;
    const int r16  = lane & 15;

    int arow = row0 + r16;
    int arow_c = arow < N_NODES ? arow : (N_NODES - 1);

    f32x4 zac[4] = {{0,0,0,0},{0,0,0,0},{0,0,0,0},{0,0,0,0}};
#pragma unroll
    for (int kk = 0; kk < 2; ++kk) {
        bf16x8 a = *(const bf16x8*)((const u16*)H + (size_t)arow_c * 64 + kk * 32 + g4 * 8);
#pragma unroll
        for (int t = 0; t < 4; ++t) {
            bf16x8 b = *(const bf16x8*)&sP[((kk * 4 + t) * 64 + lane) * 8];
            zac[t] = __builtin_amdgcn_mfma_f32_16x16x32_bf16(a, b, zac[t], 0, 0, 0);
        }
    }

#pragma unroll
    for (int r = 0; r < 4; ++r) {
        int row = row0 + g4 * 4 + r;
#pragma unroll
        for (int t = 0; t < 4; ++t) {
            float v = zac[t][r] + bp[t * 16 + r16];
            v = fmaxf(v, 0.f);
            zt[wv][g4 * 4 + r][t * 16 + r16] = f2bf(v);
            if (row < N_NODES)
                out[(size_t)Z_OFF + (size_t)row * 64 + t * 16 + r16] = v;
        }
    }
    __syncthreads();

    f32x4 lac = {0, 0, 0, 0};
#pragma unroll
    for (int kk = 0; kk < 2; ++kk) {
        bf16x8 a = *(const bf16x8*)&zt[wv][r16][kk * 32 + g4 * 8];
        bf16x8 b = *(const bf16x8*)&sC[(kk * 64 + lane) * 8];
        lac = __builtin_amdgcn_mfma_f32_16x16x32_bf16(a, b, lac, 0, 0, 0);
    }
#pragma unroll
    for (int r = 0; r < 4; ++r) {
        int row = row0 + g4 * 4 + r;
        if (row < N_NODES && r16 < NCLS)
            out[(size_t)row * NCLS + r16] = lac[r] + bc[r16];
    }
}

extern "C" void kernel_launch(void* const* d_in, const int* in_sizes, int n_in,
                              void* d_out, int out_size, void* d_ws, size_t ws_size,
                              hipStream_t stream) {
    const float* x  = (const float*)d_in[0];
    const int*   ei = (const int*)d_in[1];
    const float* W1 = (const float*)d_in[2];
    const float* b1 = (const float*)d_in[3];
    const float* W2 = (const float*)d_in[4];
    const float* b2 = (const float*)d_in[5];
    const float* Wp = (const float*)d_in[6];
    const float* bp = (const float*)d_in[7];
    const float* Wc = (const float*)d_in[8];
    const float* bc = (const float*)d_in[9];
    float* out = (float*)d_out;

    char* ws   = (char*)d_ws;
    int*  cnt  = (int*)(ws + OFF_CNT);
    int*  ovfc = (int*)(ws + OFF_OVFC);
    int*  ovf  = (int*)(ws + OFF_OVF);
    int*  col  = (int*)(ws + OFF_COL);
    u16*  wt   = (u16*)(ws + OFF_WT);
    u16*  g    = (u16*)(ws + OFF_G);
    u16*  h    = (u16*)(ws + OFF_H);

    k_wprep<<<100, 256, 0, stream>>>(W1, W2, Wp, Wc, wt, cnt);
    k_fill<<<(NE / 512) * NPART, 256, 0, stream>>>(ei, cnt, col, ovfc, ovf);
    k_gemm<IN_CH, false><<<GEMMB, 256, 0, stream>>>(x, wt + WT_W1, cnt, g);
    k_agg<<<N_NODES / 4, 256, 0, stream>>>(g, col, cnt, ovfc, ovf, b1, h);
    k_gemm<HID_D, true><<<GEMMB, 256, 0, stream>>>(h, wt + WT_W2, cnt, g);
    k_agg<<<N_NODES / 4, 256, 0, stream>>>(g, col, cnt, ovfc, ovf, b2, h);
    k_mlp<<<GEMMB, 256, 0, stream>>>(h, wt, bp, bc, out);
}